// Round 5
// baseline (125.326 us; speedup 1.0000x reference)
//
#include <hip/hip_runtime.h>

// QRNN fo-pool: B=8, C=256, H=256, T=4096, K=2
// PX (x -> xq: B-operand in MFMA-fragment-packed bf16 order, both conv taps),
// PW (Wz/Wf/Wo -> aq: A-operand fragment-packed bf16 [3H stacked][2C]),
// G  (zero-LDS zero-barrier MFMA GEMM: direct coalesced L2 loads -> MFMA;
//     epilogue bias+act; z,o stored bf16, f stored fp32),
// S1 (chunk=32 aggregates), S2 (aggregate scan -> carry_in),
// S3 (local re-scan with carry folded; writes c and h=o*c).
//
// Fragment packing (both A and B use the SAME lane->k map, so any k-permutation
// cancels inside the MFMA dot product):
//   buf[((frag16*16 + kstep)*64 + lane)*8 + j] = M[frag16*16 + (lane&15)][kstep*32 + (lane>>4)*8 + j]

typedef unsigned short ushort_t;
typedef __attribute__((ext_vector_type(8))) short short8_t;
typedef __attribute__((ext_vector_type(4))) float f32x4;

#define B_ 8
#define C_ 256
#define H_ 256
#define T_ 4096
#define TCH 32          // scan chunk length
#define NCH 128         // T_/TCH

__device__ __forceinline__ unsigned short f2bf(float f) {
  unsigned int u = __float_as_uint(f);
  u += 0x7fffu + ((u >> 16) & 1u);   // RNE
  return (unsigned short)(u >> 16);
}
__device__ __forceinline__ float bf2f(unsigned short u) {
  return __uint_as_float(((unsigned int)u) << 16);
}
__device__ __forceinline__ float sigm(float v) { return 1.f / (1.f + __expf(-v)); }
__device__ __forceinline__ float tanh_f(float v) { return 2.f / (1.f + __expf(-2.f * v)) - 1.f; }

// ---------------- PX: x [B][C][T] f32 -> xq fragment-packed bf16 -------------------------
// xq frag element (b, tf, ks, lane, j): t = 16*tf + (lane&15); k = 32*ks + (lane>>4)*8 + j
//   k < 256  -> x[b][k][t]      (tap 1: current input)
//   k >= 256 -> x[b][k-256][t-1] (tap 0: previous input; 0 at t==0)
__global__ __launch_bounds__(256) void qrnn_pack_x(const float* __restrict__ x,
                                                   ushort_t* __restrict__ xq) {
  __shared__ float tile[32][132];      // c-local 32 x t-local [t0-4, t0+128)
  const int tid = threadIdx.x;
  const int t0 = blockIdx.x * 128, c0 = blockIdx.y * 32, b = blockIdx.z;
#pragma unroll
  for (int p = 0; p < 5; ++p) {
    const int idx = tid + p * 256;     // 1056 float4 slots = 32 rows x 33
    if (idx < 1056) {
      const int row = idx / 33, q = idx % 33;
      const int tg = t0 - 4 + q * 4;
      float4 v = make_float4(0.f, 0.f, 0.f, 0.f);
      if (tg >= 0)
        v = *reinterpret_cast<const float4*>(x + ((size_t)(b * C_ + c0 + row)) * T_ + tg);
      tile[row][q * 4 + 0] = v.x; tile[row][q * 4 + 1] = v.y;
      tile[row][q * 4 + 2] = v.z; tile[row][q * 4 + 3] = v.w;
    }
  }
  __syncthreads();
  const int ks0 = c0 >> 5;             // k-step for tap1 region
#pragma unroll
  for (int q2 = 0; q2 < 2; ++q2) {
    const int p = tid + q2 * 256;      // 512 (tf,lane) pairs
    const int tfl = p >> 6, lane = p & 63;
    const int l15 = lane & 15, g8 = (lane >> 4) * 8;
    const int tcol = tfl * 16 + l15;   // t-local in [0,128)
    ushort_t o0[8], o1[8];
#pragma unroll
    for (int j = 0; j < 8; ++j) {
      o0[j] = f2bf(tile[g8 + j][tcol + 4]);   // x[t]
      o1[j] = f2bf(tile[g8 + j][tcol + 3]);   // x[t-1]
    }
    const int tf = (t0 >> 4) + tfl;
    ushort_t* d0 = xq + ((size_t)((b * 256 + tf) * 16 + ks0) * 64 + lane) * 8;
    ushort_t* d1 = xq + ((size_t)((b * 256 + tf) * 16 + 8 + ks0) * 64 + lane) * 8;
    *reinterpret_cast<uint4*>(d0) = *reinterpret_cast<uint4*>(&o0[0]);
    *reinterpret_cast<uint4*>(d1) = *reinterpret_cast<uint4*>(&o1[0]);
  }
}

// ---------------- PW: Wz/Wf/Wo -> aq fragment-packed [3H][2C] ----------------------------
// aq row m = g*256 + h; k<256 -> W[h][k][1], k>=256 -> W[h][k-256][0]
__global__ __launch_bounds__(256) void qrnn_pack_w(const float* __restrict__ Wz,
                                                   const float* __restrict__ Wf,
                                                   const float* __restrict__ Wo,
                                                   ushort_t* __restrict__ aq) {
  const int idx = blockIdx.x * 256 + threadIdx.x;   // < 48*16*64 = 49152
  const int lane = idx & 63;
  const int ks = (idx >> 6) & 15;
  const int mf = idx >> 10;            // 0..47
  const int g = mf >> 4;
  const int h = (mf & 15) * 16 + (lane & 15);
  const float* W = (g == 0) ? Wz : ((g == 1) ? Wf : Wo);
  ushort_t o[8];
#pragma unroll
  for (int j = 0; j < 8; ++j) {
    const int k = ks * 32 + (lane >> 4) * 8 + j;
    const int c = k & 255;
    const int tap = (k < 256) ? 1 : 0;
    o[j] = f2bf(W[((size_t)h * C_ + c) * 2 + tap]);
  }
  *reinterpret_cast<uint4*>(aq + (size_t)idx * 8) = *reinterpret_cast<uint4*>(&o[0]);
}

// ---------------- G: zero-LDS zero-barrier MFMA GEMM [768 x 512] x [512 x 64] ------------
// 512 blocks (64 t-tiles x 8 b), 512 threads (8 waves), wave w owns m-frags [6w, 6w+6).
__global__ __launch_bounds__(512, 2) void qrnn_g(const ushort_t* __restrict__ aq,
                                                 const ushort_t* __restrict__ xq,
                                                 const float* __restrict__ bz,
                                                 const float* __restrict__ bfv,
                                                 const float* __restrict__ bo,
                                                 float* __restrict__ fb,
                                                 ushort_t* __restrict__ zb,
                                                 ushort_t* __restrict__ ob) {
  const int tid = threadIdx.x;
  const int lane = tid & 63;
  const int w = tid >> 6;
  const int l15 = lane & 15, g4 = lane >> 4;
  const int tt = blockIdx.x, b = blockIdx.y;

  const short8_t* Abase = reinterpret_cast<const short8_t*>(aq) + (size_t)(6 * w) * 16 * 64 + lane;
  const short8_t* Bbase =
      reinterpret_cast<const short8_t*>(xq) + (size_t)((b * 256 + tt * 4) * 16) * 64 + lane;

  f32x4 acc[6][4];
#pragma unroll
  for (int i = 0; i < 6; ++i)
#pragma unroll
    for (int n = 0; n < 4; ++n) acc[i][n] = (f32x4){0.f, 0.f, 0.f, 0.f};

#pragma unroll 2
  for (int ks = 0; ks < 16; ++ks) {
    short8_t a[6], bb[4];
#pragma unroll
    for (int i = 0; i < 6; ++i) a[i] = Abase[(size_t)(i * 16 + ks) * 64];
#pragma unroll
    for (int n = 0; n < 4; ++n) bb[n] = Bbase[(size_t)(n * 16 + ks) * 64];
#pragma unroll
    for (int i = 0; i < 6; ++i)
#pragma unroll
      for (int n = 0; n < 4; ++n)
        acc[i][n] = __builtin_amdgcn_mfma_f32_16x16x32_bf16(a[i], bb[n], acc[i][n], 0, 0, 0);
  }

  // epilogue: bias + activation; z,o -> bf16, f -> fp32
#pragma unroll
  for (int i = 0; i < 6; ++i) {
    const int mf = 6 * w + i;
    const int g = mf >> 4;
    const int hb0 = (mf & 15) * 16;
    const float* bias = (g == 0) ? bz : ((g == 1) ? bfv : bo);
    float bv[4];
#pragma unroll
    for (int r = 0; r < 4; ++r) bv[r] = bias[hb0 + g4 * 4 + r];
#pragma unroll
    for (int n = 0; n < 4; ++n) {
      const int t = tt * 64 + n * 16 + l15;   // C/D map: col = lane&15
#pragma unroll
      for (int r = 0; r < 4; ++r) {
        const int h = hb0 + g4 * 4 + r;       // C/D map: row = (lane>>4)*4 + reg
        const float v = acc[i][n][r] + bv[r];
        const size_t off = ((size_t)b * H_ + h) * T_ + t;
        if (g == 0)      zb[off] = f2bf(tanh_f(v));
        else if (g == 1) fb[off] = sigm(v);
        else             ob[off] = f2bf(sigm(v));
      }
    }
  }
}

// ---------------- S1: per-chunk aggregates only (P = cumprod f, C = local end value) ----
__global__ __launch_bounds__(256) void qrnn_s1(const float* __restrict__ fb,
                                               const ushort_t* __restrict__ zb,
                                               float* __restrict__ aggP,
                                               float* __restrict__ aggC) {
  __shared__ float lf[256][33];
  __shared__ ushort_t lzs[256][36];
  const int tid = threadIdx.x;
  const int chunk = blockIdx.x;
  const int b = blockIdx.y;
  const int t0 = chunk * TCH;
  const float* fbase = fb + (size_t)b * H_ * T_;
  const ushort_t* zbase = zb + (size_t)b * H_ * T_;
  const int lr = tid >> 3, lc = (tid & 7) * 4;
#pragma unroll
  for (int pass = 0; pass < 8; ++pass) {
    const int row = pass * 32 + lr;
    float4 fv = *reinterpret_cast<const float4*>(fbase + (size_t)row * T_ + t0 + lc);
    uint2 zv = *reinterpret_cast<const uint2*>(zbase + (size_t)row * T_ + t0 + lc);
    lf[row][lc] = fv.x; lf[row][lc + 1] = fv.y; lf[row][lc + 2] = fv.z; lf[row][lc + 3] = fv.w;
    lzs[row][lc] = (ushort_t)(zv.x & 0xffff); lzs[row][lc + 1] = (ushort_t)(zv.x >> 16);
    lzs[row][lc + 2] = (ushort_t)(zv.y & 0xffff); lzs[row][lc + 3] = (ushort_t)(zv.y >> 16);
  }
  __syncthreads();
  float c = 0.f, p = 1.f;
#pragma unroll
  for (int t = 0; t < TCH; ++t) {
    const float f = lf[tid][t], z = bf2f(lzs[tid][t]);
    c = f * (c - z) + z;   // = f*c + (1-f)*z
    p *= f;
  }
  aggP[((size_t)b * NCH + chunk) * H_ + tid] = p;
  aggC[((size_t)b * NCH + chunk) * H_ + tid] = c;
}

// ---------------- S2: scan over chunk aggregates -> carry_in -----------------------------
__global__ __launch_bounds__(256) void qrnn_s2(const float* __restrict__ aggP,
                                               const float* __restrict__ aggC,
                                               float* __restrict__ cin) {
  const int b = blockIdx.x, h = threadIdx.x;
  float carry = 0.f;
  for (int jb = 0; jb < NCH; jb += 8) {
    float P[8], Cv[8];
#pragma unroll
    for (int u = 0; u < 8; ++u) {
      P[u] = aggP[((size_t)b * NCH + jb + u) * H_ + h];
      Cv[u] = aggC[((size_t)b * NCH + jb + u) * H_ + h];
    }
#pragma unroll
    for (int u = 0; u < 8; ++u) {
      cin[((size_t)b * NCH + jb + u) * H_ + h] = carry;
      carry = Cv[u] + P[u] * carry;
    }
  }
}

// ---------------- S3: local re-scan with carry folded; write c and h = o*c --------------
__global__ __launch_bounds__(256) void qrnn_s3(const float* __restrict__ fb,
                                               const ushort_t* __restrict__ zb,
                                               const ushort_t* __restrict__ ob,
                                               const float* __restrict__ cin,
                                               float* __restrict__ outc,
                                               float* __restrict__ outh) {
  __shared__ float lf[128][33];
  __shared__ ushort_t lzs[128][36];
  __shared__ ushort_t los[128][36];
  const int tid = threadIdx.x;
  const int chunk = blockIdx.x;          // 0..127
  const int h0 = blockIdx.y * 128;       // 0 or 128
  const int b = blockIdx.z;
  const int t0 = chunk * TCH;
  const float* fbase = fb + (size_t)b * H_ * T_;
  const ushort_t* zbase = zb + (size_t)b * H_ * T_;
  const ushort_t* obase = ob + (size_t)b * H_ * T_;
#pragma unroll
  for (int i = 0; i < 4; ++i) {
    const int j = tid + i * 256;         // 0..1023
    const int row = j >> 3, c4 = (j & 7) * 4;
    const size_t goff = (size_t)(h0 + row) * T_ + t0 + c4;
    float4 fv = *reinterpret_cast<const float4*>(fbase + goff);
    uint2 zv = *reinterpret_cast<const uint2*>(zbase + goff);
    uint2 ov = *reinterpret_cast<const uint2*>(obase + goff);
    lf[row][c4] = fv.x; lf[row][c4 + 1] = fv.y; lf[row][c4 + 2] = fv.z; lf[row][c4 + 3] = fv.w;
    lzs[row][c4] = (ushort_t)(zv.x & 0xffff); lzs[row][c4 + 1] = (ushort_t)(zv.x >> 16);
    lzs[row][c4 + 2] = (ushort_t)(zv.y & 0xffff); lzs[row][c4 + 3] = (ushort_t)(zv.y >> 16);
    los[row][c4] = (ushort_t)(ov.x & 0xffff); los[row][c4 + 1] = (ushort_t)(ov.x >> 16);
    los[row][c4 + 2] = (ushort_t)(ov.y & 0xffff); los[row][c4 + 3] = (ushort_t)(ov.y >> 16);
  }
  __syncthreads();
  if (tid < 128) {
    float c = cin[((size_t)b * NCH + chunk) * H_ + h0 + tid];
#pragma unroll
    for (int t = 0; t < TCH; ++t) {
      const float f = lf[tid][t], z = bf2f(lzs[tid][t]);
      c = f * (c - z) + z;
      lf[tid][t] = c;                               // c (f slot reused)
      lzs[tid][t] = f2bf(bf2f(los[tid][t]) * c);    // placeholder; real h below
    }
    // store h as fp32 via second pass to keep precision: recompute o*c into los-slot pairs
  }
  __syncthreads();
  float* cb = outc + (size_t)b * H_ * T_;
  float* hb = outh + (size_t)b * H_ * T_;
#pragma unroll
  for (int i = 0; i < 4; ++i) {
    const int j = tid + i * 256;
    const int row = j >> 3, c4 = (j & 7) * 4;
    const size_t goff = (size_t)(h0 + row) * T_ + t0 + c4;
    float4 cv = make_float4(lf[row][c4], lf[row][c4 + 1], lf[row][c4 + 2], lf[row][c4 + 3]);
    float4 hv = make_float4(bf2f(los[row][c4]) * cv.x, bf2f(los[row][c4 + 1]) * cv.y,
                            bf2f(los[row][c4 + 2]) * cv.z, bf2f(los[row][c4 + 3]) * cv.w);
    *reinterpret_cast<float4*>(cb + goff) = cv;
    *reinterpret_cast<float4*>(hb + goff) = hv;
  }
}

extern "C" void kernel_launch(void* const* d_in, const int* in_sizes, int n_in,
                              void* d_out, int out_size, void* d_ws, size_t ws_size,
                              hipStream_t stream) {
  const float* x  = (const float*)d_in[0];
  const float* Wz = (const float*)d_in[1];
  const float* bz = (const float*)d_in[2];
  const float* Wf = (const float*)d_in[3];
  const float* bfv= (const float*)d_in[4];
  const float* Wo = (const float*)d_in[5];
  const float* bo = (const float*)d_in[6];
  // Wi/bi (d_in[7], d_in[8]) are dead in the reference.

  float* outh = (float*)d_out;                        // [B][H][T]
  float* outc = outh + (size_t)B_ * H_ * T_;          // [B][H][T]

  // workspace layout (bytes)
  constexpr size_t XQ_OFF  = 0;                       // 33,554,432 (frag-packed x, both taps)
  constexpr size_t AQ_OFF  = 33554432;                //    786,432 (frag-packed Wcat)
  constexpr size_t FB_OFF  = 34340864;                // 33,554,432 (f gate fp32)
  constexpr size_t ZB_OFF  = 67895296;                // 16,777,216 (z gate bf16)
  constexpr size_t OB_OFF  = 84672512;                // 16,777,216 (o gate bf16)
  constexpr size_t AGP_OFF = 101449728;               //  1,048,576
  constexpr size_t AGC_OFF = 102498304;               //  1,048,576
  constexpr size_t CIN_OFF = 103546880;               //  1,048,576
  constexpr size_t WS_NEED = 104595456;
  if (ws_size < WS_NEED) return;

  ushort_t* xq = (ushort_t*)((char*)d_ws + XQ_OFF);
  ushort_t* aq = (ushort_t*)((char*)d_ws + AQ_OFF);
  float* fbuf  = (float*)((char*)d_ws + FB_OFF);
  ushort_t* zb = (ushort_t*)((char*)d_ws + ZB_OFF);
  ushort_t* ob = (ushort_t*)((char*)d_ws + OB_OFF);
  float* aggP  = (float*)((char*)d_ws + AGP_OFF);
  float* aggC  = (float*)((char*)d_ws + AGC_OFF);
  float* cin   = (float*)((char*)d_ws + CIN_OFF);

  qrnn_pack_x<<<dim3(T_ / 128, C_ / 32, B_), 256, 0, stream>>>(x, xq);
  qrnn_pack_w<<<dim3(192), 256, 0, stream>>>(Wz, Wf, Wo, aq);
  qrnn_g<<<dim3(T_ / 64, B_), 512, 0, stream>>>(aq, xq, bz, bfv, bo, fbuf, zb, ob);
  qrnn_s1<<<dim3(NCH, B_), 256, 0, stream>>>(fbuf, zb, aggP, aggC);
  qrnn_s2<<<dim3(B_), 256, 0, stream>>>(aggP, aggC, cin);
  qrnn_s3<<<dim3(NCH, 2, B_), 256, 0, stream>>>(fbuf, zb, ob, cin, outc, outh);
}

// Round 6
// 110.484 us; speedup vs baseline: 1.1343x; 1.1343x over previous
//
#include <hip/hip_runtime.h>

// QRNN fo-pool: B=8, C=256, H=256, T=4096, K=2
// PX (x -> xq frag-packed bf16, both conv taps)  [unchanged from r5]
// PW (W -> aq frag-packed, m-order = [hs][gate][hl] so BM=192 covers 64h x 3 gates)
// G  (MFMA GEMM, BM=192 BT=128 BK=64, 8 waves, gl16 staging -> linear LDS,
//     single-buffered 2-barrier loop; epilogue bias+act; z,o bf16, f fp32)
// S1 (chunk=32 aggregates), S2 (aggregate scan), S3 (re-scan + h=o*c)  [r5]

typedef unsigned short ushort_t;
typedef __attribute__((ext_vector_type(8))) short short8_t;
typedef __attribute__((ext_vector_type(4))) float f32x4;

#define B_ 8
#define C_ 256
#define H_ 256
#define T_ 4096
#define TCH 32
#define NCH 128

__device__ __forceinline__ unsigned short f2bf(float f) {
  unsigned int u = __float_as_uint(f);
  u += 0x7fffu + ((u >> 16) & 1u);
  return (unsigned short)(u >> 16);
}
__device__ __forceinline__ float bf2f(unsigned short u) {
  return __uint_as_float(((unsigned int)u) << 16);
}
__device__ __forceinline__ float sigm(float v) { return 1.f / (1.f + __expf(-v)); }
__device__ __forceinline__ float tanh_f(float v) { return 2.f / (1.f + __expf(-2.f * v)) - 1.f; }

__device__ __forceinline__ void gl16(const ushort_t* g, ushort_t* l) {
  __builtin_amdgcn_global_load_lds(
      (const __attribute__((address_space(1))) unsigned int*)g,
      (__attribute__((address_space(3))) unsigned int*)l, 16, 0, 0);
}

// ---------------- PX: x [B][C][T] f32 -> xq fragment-packed bf16 -------------------------
// xq[((b*256+tf)*16+ks)*64+lane][j]: t = 16tf+(lane&15); k = 32ks+(lane>>4)*8+j
//   k<256 -> x[b][k][t] ; k>=256 -> x[b][k-256][t-1] (0 at t==0)
__global__ __launch_bounds__(256) void qrnn_pack_x(const float* __restrict__ x,
                                                   ushort_t* __restrict__ xq) {
  __shared__ float tile[32][132];
  const int tid = threadIdx.x;
  const int t0 = blockIdx.x * 128, c0 = blockIdx.y * 32, b = blockIdx.z;
#pragma unroll
  for (int p = 0; p < 5; ++p) {
    const int idx = tid + p * 256;
    if (idx < 1056) {
      const int row = idx / 33, q = idx % 33;
      const int tg = t0 - 4 + q * 4;
      float4 v = make_float4(0.f, 0.f, 0.f, 0.f);
      if (tg >= 0)
        v = *reinterpret_cast<const float4*>(x + ((size_t)(b * C_ + c0 + row)) * T_ + tg);
      tile[row][q * 4 + 0] = v.x; tile[row][q * 4 + 1] = v.y;
      tile[row][q * 4 + 2] = v.z; tile[row][q * 4 + 3] = v.w;
    }
  }
  __syncthreads();
  const int ks0 = c0 >> 5;
#pragma unroll
  for (int q2 = 0; q2 < 2; ++q2) {
    const int p = tid + q2 * 256;
    const int tfl = p >> 6, lane = p & 63;
    const int l15 = lane & 15, g8 = (lane >> 4) * 8;
    const int tcol = tfl * 16 + l15;
    ushort_t o0[8], o1[8];
#pragma unroll
    for (int j = 0; j < 8; ++j) {
      o0[j] = f2bf(tile[g8 + j][tcol + 4]);   // x[t]
      o1[j] = f2bf(tile[g8 + j][tcol + 3]);   // x[t-1]
    }
    const int tf = (t0 >> 4) + tfl;
    ushort_t* d0 = xq + ((size_t)((b * 256 + tf) * 16 + ks0) * 64 + lane) * 8;
    ushort_t* d1 = xq + ((size_t)((b * 256 + tf) * 16 + 8 + ks0) * 64 + lane) * 8;
    *reinterpret_cast<uint4*>(d0) = *reinterpret_cast<uint4*>(&o0[0]);
    *reinterpret_cast<uint4*>(d1) = *reinterpret_cast<uint4*>(&o1[0]);
  }
}

// ---------------- PW: W -> aq frag-packed, mf = hs*12 + g*4 + hlf ------------------------
__global__ __launch_bounds__(256) void qrnn_pack_w(const float* __restrict__ Wz,
                                                   const float* __restrict__ Wf,
                                                   const float* __restrict__ Wo,
                                                   ushort_t* __restrict__ aq) {
  const int idx = blockIdx.x * 256 + threadIdx.x;   // < 48*16*64
  const int lane = idx & 63;
  const int ks = (idx >> 6) & 15;
  const int mf = idx >> 10;            // 0..47
  const int hs = mf / 12, rem = mf % 12;
  const int g = rem >> 2, hlf = rem & 3;
  const int h = hs * 64 + hlf * 16 + (lane & 15);
  const float* W = (g == 0) ? Wz : ((g == 1) ? Wf : Wo);
  ushort_t o[8];
#pragma unroll
  for (int j = 0; j < 8; ++j) {
    const int k = ks * 32 + (lane >> 4) * 8 + j;
    const int c = k & 255;
    const int tap = (k < 256) ? 1 : 0;
    o[j] = f2bf(W[((size_t)h * C_ + c) * 2 + tap]);
  }
  *reinterpret_cast<uint4*>(aq + (size_t)idx * 8) = *reinterpret_cast<uint4*>(&o[0]);
}

// ---------------- G: MFMA GEMM, block = 192m x 128t, K=512 in 8 steps of 64 --------------
__global__ __launch_bounds__(512, 4) void qrnn_g(const ushort_t* __restrict__ aq,
                                                 const ushort_t* __restrict__ xq,
                                                 const float* __restrict__ bz,
                                                 const float* __restrict__ bfv,
                                                 const float* __restrict__ bo,
                                                 float* __restrict__ fb,
                                                 ushort_t* __restrict__ zb,
                                                 ushort_t* __restrict__ ob) {
  __shared__ ushort_t As[12 * 2 * 64 * 8];   // 24KB: [mfl][ksl][lane][8]
  __shared__ ushort_t Bs[8 * 2 * 64 * 8];    // 16KB: [tfl][ksl][lane][8]
  const int tid = threadIdx.x;
  const int lane = tid & 63;
  const int wid = tid >> 6;
  const int wm = wid >> 1, wt = wid & 1;     // m-split 4, t-split 2
  const int l15 = lane & 15, g4 = lane >> 4;
  const int tt = blockIdx.x;                 // t-tile (128)
  const int hs = blockIdx.y;                 // h-strip (64)
  const int b = blockIdx.z;

  f32x4 acc[3][4];
#pragma unroll
  for (int i = 0; i < 3; ++i)
#pragma unroll
    for (int n = 0; n < 4; ++n) acc[i][n] = (f32x4){0.f, 0.f, 0.f, 0.f};

  // staging chunk ids: A c in [0,1536) = (mfl*2+ksl)*64+lane ; B c2 in [0,1024)
  const int cA0 = tid, cA1 = tid + 512, cA2 = tid + 1024;
  const int wbase = tid - lane;

  for (int kk = 0; kk < 8; ++kk) {
    // ---- stage: 3 A chunks + 2 B chunks per thread (gl16, linear LDS dest) ----
    {
      const int c = cA0;
      gl16(aq + ((size_t)((hs * 12 + (c >> 7)) * 16 + kk * 2 + ((c >> 6) & 1)) << 9) + lane * 8,
           As + (size_t)(c - lane) * 8);
    }
    {
      const int c = cA1;
      gl16(aq + ((size_t)((hs * 12 + (c >> 7)) * 16 + kk * 2 + ((c >> 6) & 1)) << 9) + lane * 8,
           As + (size_t)(c - lane) * 8);
    }
    {
      const int c = cA2;
      gl16(aq + ((size_t)((hs * 12 + (c >> 7)) * 16 + kk * 2 + ((c >> 6) & 1)) << 9) + lane * 8,
           As + (size_t)(c - lane) * 8);
    }
#pragma unroll
    for (int q = 0; q < 2; ++q) {
      const int c2 = tid + q * 512;
      gl16(xq + ((size_t)((b * 256 + tt * 8 + (c2 >> 7)) * 16 + kk * 2 + ((c2 >> 6) & 1)) << 9) +
               lane * 8,
           Bs + (size_t)(c2 - lane) * 8);
    }
    __syncthreads();   // drains gl16 (vmcnt 0) for all waves

    // ---- compute: 14 ds_read_b128, 24 MFMA per wave ----
#pragma unroll
    for (int l = 0; l < 2; ++l) {
      short8_t a[3], bb[4];
#pragma unroll
      for (int i = 0; i < 3; ++i)
        a[i] = *reinterpret_cast<const short8_t*>(
            &As[(size_t)((((wm * 3 + i) * 2 + l) * 64) + lane) * 8]);
#pragma unroll
      for (int n = 0; n < 4; ++n)
        bb[n] = *reinterpret_cast<const short8_t*>(
            &Bs[(size_t)((((wt * 4 + n) * 2 + l) * 64) + lane) * 8]);
#pragma unroll
      for (int i = 0; i < 3; ++i)
#pragma unroll
        for (int n = 0; n < 4; ++n)
          acc[i][n] = __builtin_amdgcn_mfma_f32_16x16x32_bf16(a[i], bb[n], acc[i][n], 0, 0, 0);
    }
    __syncthreads();   // release LDS for next staging
  }

  // ---- epilogue: bias + activation; z,o bf16, f fp32; layout [b][h][t] ----
#pragma unroll
  for (int i = 0; i < 3; ++i) {
    const int mfl = wm * 3 + i;          // 0..11
    const int g = mfl >> 2;              // gate 0=z 1=f 2=o
    const int hl0 = (mfl & 3) * 16;
    const float* bias = (g == 0) ? bz : ((g == 1) ? bfv : bo);
#pragma unroll
    for (int r = 0; r < 4; ++r) {
      const int h = hs * 64 + hl0 + g4 * 4 + r;     // C/D: row=(lane>>4)*4+reg
      const float bvv = bias[h];
      const size_t rowoff = ((size_t)b * H_ + h) * T_;
#pragma unroll
      for (int n = 0; n < 4; ++n) {
        const int t = tt * 128 + wt * 64 + n * 16 + l15;   // C/D: col=lane&15
        const float v = acc[i][n][r] + bvv;
        if (g == 0)      zb[rowoff + t] = f2bf(tanh_f(v));
        else if (g == 1) fb[rowoff + t] = sigm(v);
        else             ob[rowoff + t] = f2bf(sigm(v));
      }
    }
  }
}

// ---------------- S1: per-chunk aggregates (P = cumprod f, C = local end) ----------------
__global__ __launch_bounds__(256) void qrnn_s1(const float* __restrict__ fb,
                                               const ushort_t* __restrict__ zb,
                                               float* __restrict__ aggP,
                                               float* __restrict__ aggC) {
  __shared__ float lf[256][33];
  __shared__ ushort_t lzs[256][36];
  const int tid = threadIdx.x;
  const int chunk = blockIdx.x;
  const int b = blockIdx.y;
  const int t0 = chunk * TCH;
  const float* fbase = fb + (size_t)b * H_ * T_;
  const ushort_t* zbase = zb + (size_t)b * H_ * T_;
  const int lr = tid >> 3, lc = (tid & 7) * 4;
#pragma unroll
  for (int pass = 0; pass < 8; ++pass) {
    const int row = pass * 32 + lr;
    float4 fv = *reinterpret_cast<const float4*>(fbase + (size_t)row * T_ + t0 + lc);
    uint2 zv = *reinterpret_cast<const uint2*>(zbase + (size_t)row * T_ + t0 + lc);
    lf[row][lc] = fv.x; lf[row][lc + 1] = fv.y; lf[row][lc + 2] = fv.z; lf[row][lc + 3] = fv.w;
    lzs[row][lc] = (ushort_t)(zv.x & 0xffff); lzs[row][lc + 1] = (ushort_t)(zv.x >> 16);
    lzs[row][lc + 2] = (ushort_t)(zv.y & 0xffff); lzs[row][lc + 3] = (ushort_t)(zv.y >> 16);
  }
  __syncthreads();
  float c = 0.f, p = 1.f;
#pragma unroll
  for (int t = 0; t < TCH; ++t) {
    const float f = lf[tid][t], z = bf2f(lzs[tid][t]);
    c = f * (c - z) + z;
    p *= f;
  }
  aggP[((size_t)b * NCH + chunk) * H_ + tid] = p;
  aggC[((size_t)b * NCH + chunk) * H_ + tid] = c;
}

// ---------------- S2: scan over chunk aggregates -> carry_in -----------------------------
__global__ __launch_bounds__(256) void qrnn_s2(const float* __restrict__ aggP,
                                               const float* __restrict__ aggC,
                                               float* __restrict__ cin) {
  const int b = blockIdx.x, h = threadIdx.x;
  float carry = 0.f;
  for (int jb = 0; jb < NCH; jb += 8) {
    float P[8], Cv[8];
#pragma unroll
    for (int u = 0; u < 8; ++u) {
      P[u] = aggP[((size_t)b * NCH + jb + u) * H_ + h];
      Cv[u] = aggC[((size_t)b * NCH + jb + u) * H_ + h];
    }
#pragma unroll
    for (int u = 0; u < 8; ++u) {
      cin[((size_t)b * NCH + jb + u) * H_ + h] = carry;
      carry = Cv[u] + P[u] * carry;
    }
  }
}

// ---------------- S3: local re-scan with carry folded; write c and h = o*c --------------
__global__ __launch_bounds__(256) void qrnn_s3(const float* __restrict__ fb,
                                               const ushort_t* __restrict__ zb,
                                               const ushort_t* __restrict__ ob,
                                               const float* __restrict__ cin,
                                               float* __restrict__ outc,
                                               float* __restrict__ outh) {
  __shared__ float lf[128][33];
  __shared__ ushort_t lzs[128][36];
  __shared__ ushort_t los[128][36];
  const int tid = threadIdx.x;
  const int chunk = blockIdx.x;
  const int h0 = blockIdx.y * 128;
  const int b = blockIdx.z;
  const int t0 = chunk * TCH;
  const float* fbase = fb + (size_t)b * H_ * T_;
  const ushort_t* zbase = zb + (size_t)b * H_ * T_;
  const ushort_t* obase = ob + (size_t)b * H_ * T_;
#pragma unroll
  for (int i = 0; i < 4; ++i) {
    const int j = tid + i * 256;
    const int row = j >> 3, c4 = (j & 7) * 4;
    const size_t goff = (size_t)(h0 + row) * T_ + t0 + c4;
    float4 fv = *reinterpret_cast<const float4*>(fbase + goff);
    uint2 zv = *reinterpret_cast<const uint2*>(zbase + goff);
    uint2 ov = *reinterpret_cast<const uint2*>(obase + goff);
    lf[row][c4] = fv.x; lf[row][c4 + 1] = fv.y; lf[row][c4 + 2] = fv.z; lf[row][c4 + 3] = fv.w;
    lzs[row][c4] = (ushort_t)(zv.x & 0xffff); lzs[row][c4 + 1] = (ushort_t)(zv.x >> 16);
    lzs[row][c4 + 2] = (ushort_t)(zv.y & 0xffff); lzs[row][c4 + 3] = (ushort_t)(zv.y >> 16);
    los[row][c4] = (ushort_t)(ov.x & 0xffff); los[row][c4 + 1] = (ushort_t)(ov.x >> 16);
    los[row][c4 + 2] = (ushort_t)(ov.y & 0xffff); los[row][c4 + 3] = (ushort_t)(ov.y >> 16);
  }
  __syncthreads();
  if (tid < 128) {
    float c = cin[((size_t)b * NCH + chunk) * H_ + h0 + tid];
#pragma unroll
    for (int t = 0; t < TCH; ++t) {
      const float f = lf[tid][t], z = bf2f(lzs[tid][t]);
      c = f * (c - z) + z;
      lf[tid][t] = c;
    }
  }
  __syncthreads();
  float* cb = outc + (size_t)b * H_ * T_;
  float* hb = outh + (size_t)b * H_ * T_;
#pragma unroll
  for (int i = 0; i < 4; ++i) {
    const int j = tid + i * 256;
    const int row = j >> 3, c4 = (j & 7) * 4;
    const size_t goff = (size_t)(h0 + row) * T_ + t0 + c4;
    float4 cv = make_float4(lf[row][c4], lf[row][c4 + 1], lf[row][c4 + 2], lf[row][c4 + 3]);
    float4 hv = make_float4(bf2f(los[row][c4]) * cv.x, bf2f(los[row][c4 + 1]) * cv.y,
                            bf2f(los[row][c4 + 2]) * cv.z, bf2f(los[row][c4 + 3]) * cv.w);
    *reinterpret_cast<float4*>(cb + goff) = cv;
    *reinterpret_cast<float4*>(hb + goff) = hv;
  }
}

extern "C" void kernel_launch(void* const* d_in, const int* in_sizes, int n_in,
                              void* d_out, int out_size, void* d_ws, size_t ws_size,
                              hipStream_t stream) {
  const float* x  = (const float*)d_in[0];
  const float* Wz = (const float*)d_in[1];
  const float* bz = (const float*)d_in[2];
  const float* Wf = (const float*)d_in[3];
  const float* bfv= (const float*)d_in[4];
  const float* Wo = (const float*)d_in[5];
  const float* bo = (const float*)d_in[6];

  float* outh = (float*)d_out;                        // [B][H][T]
  float* outc = outh + (size_t)B_ * H_ * T_;          // [B][H][T]

  constexpr size_t XQ_OFF  = 0;                       // 33,554,432
  constexpr size_t AQ_OFF  = 33554432;                //    786,432
  constexpr size_t FB_OFF  = 34340864;                // 33,554,432 (f fp32)
  constexpr size_t ZB_OFF  = 67895296;                // 16,777,216 (z bf16)
  constexpr size_t OB_OFF  = 84672512;                // 16,777,216 (o bf16)
  constexpr size_t AGP_OFF = 101449728;               //  1,048,576
  constexpr size_t AGC_OFF = 102498304;               //  1,048,576
  constexpr size_t CIN_OFF = 103546880;               //  1,048,576
  constexpr size_t WS_NEED = 104595456;
  if (ws_size < WS_NEED) return;

  ushort_t* xq = (ushort_t*)((char*)d_ws + XQ_OFF);
  ushort_t* aq = (ushort_t*)((char*)d_ws + AQ_OFF);
  float* fbuf  = (float*)((char*)d_ws + FB_OFF);
  ushort_t* zb = (ushort_t*)((char*)d_ws + ZB_OFF);
  ushort_t* ob = (ushort_t*)((char*)d_ws + OB_OFF);
  float* aggP  = (float*)((char*)d_ws + AGP_OFF);
  float* aggC  = (float*)((char*)d_ws + AGC_OFF);
  float* cin   = (float*)((char*)d_ws + CIN_OFF);

  qrnn_pack_x<<<dim3(T_ / 128, C_ / 32, B_), 256, 0, stream>>>(x, xq);
  qrnn_pack_w<<<dim3(192), 256, 0, stream>>>(Wz, Wf, Wo, aq);
  qrnn_g<<<dim3(T_ / 128, 4, B_), 512, 0, stream>>>(aq, xq, bz, bfv, bo, fbuf, zb, ob);
  qrnn_s1<<<dim3(NCH, B_), 256, 0, stream>>>(fbuf, zb, aggP, aggC);
  qrnn_s2<<<dim3(B_), 256, 0, stream>>>(aggP, aggC, cin);
  qrnn_s3<<<dim3(NCH, 2, B_), 256, 0, stream>>>(fbuf, zb, ob, cin, outc, outh);
}

// Round 7
// 100.112 us; speedup vs baseline: 1.2519x; 1.1036x over previous
//
#include <hip/hip_runtime.h>

// QRNN fo-pool: B=8, C=256, H=256, T=4096, K=2
// PX (x -> xq frag-packed bf16, both conv taps)
// PW (W -> aq frag-packed, m-order = [hs][gate][hl])
// G  (MFMA GEMM 192x128, XCD-local grid decomposition (b = bid&7), gl16 staging;
//     fused epilogue: z,f -> LDS -> chunk=32 scan -> c_local fp32 + cumprod bf16
//     coalesced, chunk aggregates, o bf16 direct)
// S2 (aggregate scan -> carry_in), S3 (elementwise c = cl + P*carry; h = o*c)

typedef unsigned short ushort_t;
typedef __attribute__((ext_vector_type(8))) short short8_t;
typedef __attribute__((ext_vector_type(4))) float f32x4;

#define B_ 8
#define C_ 256
#define H_ 256
#define T_ 4096
#define TCH 32
#define NCH 128
#define LZP 129   // LDS row pad (floats): bank = (h + t) % 32 -> conflict-free scan

__device__ __forceinline__ unsigned short f2bf(float f) {
  unsigned int u = __float_as_uint(f);
  u += 0x7fffu + ((u >> 16) & 1u);
  return (unsigned short)(u >> 16);
}
__device__ __forceinline__ float bf2f(unsigned short u) {
  return __uint_as_float(((unsigned int)u) << 16);
}
__device__ __forceinline__ float sigm(float v) { return 1.f / (1.f + __expf(-v)); }
__device__ __forceinline__ float tanh_f(float v) { return 2.f / (1.f + __expf(-2.f * v)) - 1.f; }

__device__ __forceinline__ void gl16(const ushort_t* g, ushort_t* l) {
  __builtin_amdgcn_global_load_lds(
      (const __attribute__((address_space(1))) unsigned int*)g,
      (__attribute__((address_space(3))) unsigned int*)l, 16, 0, 0);
}

// ---------------- PX: x [B][C][T] f32 -> xq fragment-packed bf16 -------------------------
// xq[((b*256+tf)*16+ks)*64+lane][j]: t = 16tf+(lane&15); k = 32ks+(lane>>4)*8+j
//   k<256 -> x[b][k][t] ; k>=256 -> x[b][k-256][t-1] (0 at t==0)
__global__ __launch_bounds__(256) void qrnn_pack_x(const float* __restrict__ x,
                                                   ushort_t* __restrict__ xq) {
  __shared__ float tile[32][132];
  const int tid = threadIdx.x;
  const int t0 = blockIdx.x * 128, c0 = blockIdx.y * 32, b = blockIdx.z;
#pragma unroll
  for (int p = 0; p < 5; ++p) {
    const int idx = tid + p * 256;
    if (idx < 1056) {
      const int row = idx / 33, q = idx % 33;
      const int tg = t0 - 4 + q * 4;
      float4 v = make_float4(0.f, 0.f, 0.f, 0.f);
      if (tg >= 0)
        v = *reinterpret_cast<const float4*>(x + ((size_t)(b * C_ + c0 + row)) * T_ + tg);
      tile[row][q * 4 + 0] = v.x; tile[row][q * 4 + 1] = v.y;
      tile[row][q * 4 + 2] = v.z; tile[row][q * 4 + 3] = v.w;
    }
  }
  __syncthreads();
  const int ks0 = c0 >> 5;
#pragma unroll
  for (int q2 = 0; q2 < 2; ++q2) {
    const int p = tid + q2 * 256;
    const int tfl = p >> 6, lane = p & 63;
    const int l15 = lane & 15, g8 = (lane >> 4) * 8;
    const int tcol = tfl * 16 + l15;
    ushort_t o0[8], o1[8];
#pragma unroll
    for (int j = 0; j < 8; ++j) {
      o0[j] = f2bf(tile[g8 + j][tcol + 4]);   // x[t]
      o1[j] = f2bf(tile[g8 + j][tcol + 3]);   // x[t-1]
    }
    const int tf = (t0 >> 4) + tfl;
    ushort_t* d0 = xq + ((size_t)((b * 256 + tf) * 16 + ks0) * 64 + lane) * 8;
    ushort_t* d1 = xq + ((size_t)((b * 256 + tf) * 16 + 8 + ks0) * 64 + lane) * 8;
    *reinterpret_cast<uint4*>(d0) = *reinterpret_cast<uint4*>(&o0[0]);
    *reinterpret_cast<uint4*>(d1) = *reinterpret_cast<uint4*>(&o1[0]);
  }
}

// ---------------- PW: W -> aq frag-packed, mf = hs*12 + g*4 + hlf ------------------------
__global__ __launch_bounds__(256) void qrnn_pack_w(const float* __restrict__ Wz,
                                                   const float* __restrict__ Wf,
                                                   const float* __restrict__ Wo,
                                                   ushort_t* __restrict__ aq) {
  const int idx = blockIdx.x * 256 + threadIdx.x;   // < 48*16*64
  const int lane = idx & 63;
  const int ks = (idx >> 6) & 15;
  const int mf = idx >> 10;            // 0..47
  const int hs = mf / 12, rem = mf % 12;
  const int g = rem >> 2, hlf = rem & 3;
  const int h = hs * 64 + hlf * 16 + (lane & 15);
  const float* W = (g == 0) ? Wz : ((g == 1) ? Wf : Wo);
  ushort_t o[8];
#pragma unroll
  for (int j = 0; j < 8; ++j) {
    const int k = ks * 32 + (lane >> 4) * 8 + j;
    const int c = k & 255;
    const int tap = (k < 256) ? 1 : 0;
    o[j] = f2bf(W[((size_t)h * C_ + c) * 2 + tap]);
  }
  *reinterpret_cast<uint4*>(aq + (size_t)idx * 8) = *reinterpret_cast<uint4*>(&o[0]);
}

// ---------------- G: MFMA GEMM 192m x 128t + fused chunk-scan epilogue -------------------
__global__ __launch_bounds__(512, 4) void qrnn_g(const ushort_t* __restrict__ aq,
                                                 const ushort_t* __restrict__ xq,
                                                 const float* __restrict__ bz,
                                                 const float* __restrict__ bfv,
                                                 const float* __restrict__ bo,
                                                 float* __restrict__ cl,
                                                 ushort_t* __restrict__ pb,
                                                 ushort_t* __restrict__ ob,
                                                 float* __restrict__ aggP,
                                                 float* __restrict__ aggC) {
  __shared__ __align__(16) char ldsu[66048];        // max(40KB staging, 2x 64*129 f32)
  ushort_t* As = (ushort_t*)ldsu;                   // 24576B [mfl][ksl][lane][8]
  ushort_t* Bs = (ushort_t*)(ldsu + 24576);         // 16384B [tfl][ksl][lane][8]
  float* lz = (float*)ldsu;                         // 33024B [64][129] (z, then c_local)
  float* lf = (float*)(ldsu + 33024);               // 33024B [64][129] (f, then cumprod)

  const int tid = threadIdx.x;
  const int lane = tid & 63;
  const int wid = tid >> 6;
  const int wm = wid >> 1, wt = wid & 1;            // m-split 4, t-split 2
  const int l15 = lane & 15, g4 = lane >> 4;
  // XCD-local decomposition: blocks with bid%8==k all process batch k -> xq slice L2-fits
  const int bid = blockIdx.x;
  const int b = bid & 7;
  const int hs = (bid >> 3) & 3;
  const int tt = bid >> 5;

  f32x4 acc[3][4];
#pragma unroll
  for (int i = 0; i < 3; ++i)
#pragma unroll
    for (int n = 0; n < 4; ++n) acc[i][n] = (f32x4){0.f, 0.f, 0.f, 0.f};

  for (int kk = 0; kk < 8; ++kk) {
    // stage: 3 A chunks + 2 B chunks per thread (gl16, linear LDS dest)
#pragma unroll
    for (int q = 0; q < 3; ++q) {
      const int c = tid + q * 512;
      gl16(aq + ((size_t)((hs * 12 + (c >> 7)) * 16 + kk * 2 + ((c >> 6) & 1)) << 9) + lane * 8,
           As + (size_t)(c - lane) * 8);
    }
#pragma unroll
    for (int q = 0; q < 2; ++q) {
      const int c2 = tid + q * 512;
      gl16(xq + ((size_t)((b * 256 + tt * 8 + (c2 >> 7)) * 16 + kk * 2 + ((c2 >> 6) & 1)) << 9) +
               lane * 8,
           Bs + (size_t)(c2 - lane) * 8);
    }
    __syncthreads();
#pragma unroll
    for (int l = 0; l < 2; ++l) {
      short8_t a[3], bb[4];
#pragma unroll
      for (int i = 0; i < 3; ++i)
        a[i] = *reinterpret_cast<const short8_t*>(
            &As[(size_t)((((wm * 3 + i) * 2 + l) * 64) + lane) * 8]);
#pragma unroll
      for (int n = 0; n < 4; ++n)
        bb[n] = *reinterpret_cast<const short8_t*>(
            &Bs[(size_t)((((wt * 4 + n) * 2 + l) * 64) + lane) * 8]);
#pragma unroll
      for (int i = 0; i < 3; ++i)
#pragma unroll
        for (int n = 0; n < 4; ++n)
          acc[i][n] = __builtin_amdgcn_mfma_f32_16x16x32_bf16(a[i], bb[n], acc[i][n], 0, 0, 0);
    }
    __syncthreads();
  }

  // ---- epilogue phase 1: bias+act; z,f -> LDS; o -> global bf16 (direct) ----
#pragma unroll
  for (int i = 0; i < 3; ++i) {
    const int mfl = wm * 3 + i;          // 0..11
    const int g = mfl >> 2;              // 0=z 1=f 2=o
    const int hl0 = (mfl & 3) * 16;
    const float* bias = (g == 0) ? bz : ((g == 1) ? bfv : bo);
#pragma unroll
    for (int r = 0; r < 4; ++r) {
      const int hl = hl0 + g4 * 4 + r;                 // C/D: row=(lane>>4)*4+reg
      const float bvv = bias[hs * 64 + hl];
#pragma unroll
      for (int n = 0; n < 4; ++n) {
        const int tl = wt * 64 + n * 16 + l15;         // C/D: col=lane&15
        const float v = acc[i][n][r] + bvv;
        if (g == 0)      lz[hl * LZP + tl] = tanh_f(v);
        else if (g == 1) lf[hl * LZP + tl] = sigm(v);
        else ob[((size_t)b * H_ + hs * 64 + hl) * T_ + tt * 128 + tl] = f2bf(sigm(v));
      }
    }
  }
  __syncthreads();

  // ---- phase 2: in-LDS chunk=32 scan (256 threads: h = tid&63, chunk = tid>>6) ----
  if (tid < 256) {
    const int h = tid & 63, ch = tid >> 6;
    float* pz = lz + h * LZP + ch * 32;
    float* pf = lf + h * LZP + ch * 32;
    float c = 0.f, p = 1.f;
#pragma unroll
    for (int t = 0; t < TCH; ++t) {
      const float f = pf[t], z = pz[t];
      c = f * (c - z) + z;     // = f*c + (1-f)*z
      p *= f;
      pz[t] = c;               // c_local
      pf[t] = p;               // cumprod
    }
    const int chunkg = tt * 4 + ch;
    aggP[((size_t)b * NCH + chunkg) * H_ + hs * 64 + h] = p;
    aggC[((size_t)b * NCH + chunkg) * H_ + hs * 64 + h] = c;
  }
  __syncthreads();

  // ---- phase 3: coalesced write-out: c_local fp32, cumprod bf16 ----
  float* clb = cl + ((size_t)b * H_ + hs * 64) * T_ + tt * 128;
#pragma unroll
  for (int q = 0; q < 4; ++q) {
    const int j = tid + q * 512;         // 2048 float4 units over [64][128]
    const int row = j >> 5, col = (j & 31) * 4;
    float4 v = make_float4(lz[row * LZP + col], lz[row * LZP + col + 1],
                           lz[row * LZP + col + 2], lz[row * LZP + col + 3]);
    *reinterpret_cast<float4*>(clb + (size_t)row * T_ + col) = v;
  }
  ushort_t* pbb = pb + ((size_t)b * H_ + hs * 64) * T_ + tt * 128;
#pragma unroll
  for (int q = 0; q < 2; ++q) {
    const int j = tid + q * 512;         // 1024 uint4 units (8 bf16)
    const int row = j >> 4, col = (j & 15) * 8;
    ushort_t o8[8];
#pragma unroll
    for (int k = 0; k < 8; ++k) o8[k] = f2bf(lf[row * LZP + col + k]);
    *reinterpret_cast<uint4*>(pbb + (size_t)row * T_ + col) = *reinterpret_cast<uint4*>(&o8[0]);
  }
}

// ---------------- S2: scan over chunk aggregates -> carry_in -----------------------------
__global__ __launch_bounds__(256) void qrnn_s2(const float* __restrict__ aggP,
                                               const float* __restrict__ aggC,
                                               float* __restrict__ cin) {
  const int b = blockIdx.x, h = threadIdx.x;
  float carry = 0.f;
  for (int jb = 0; jb < NCH; jb += 8) {
    float P[8], Cv[8];
#pragma unroll
    for (int u = 0; u < 8; ++u) {
      P[u] = aggP[((size_t)b * NCH + jb + u) * H_ + h];
      Cv[u] = aggC[((size_t)b * NCH + jb + u) * H_ + h];
    }
#pragma unroll
    for (int u = 0; u < 8; ++u) {
      cin[((size_t)b * NCH + jb + u) * H_ + h] = carry;
      carry = Cv[u] + P[u] * carry;
    }
  }
}

// ---------------- S3: elementwise c = cl + P*carry; h = o*c ------------------------------
__global__ __launch_bounds__(256) void qrnn_s3(const float* __restrict__ cl,
                                               const ushort_t* __restrict__ pb,
                                               const ushort_t* __restrict__ ob,
                                               const float* __restrict__ cin,
                                               float* __restrict__ outc,
                                               float* __restrict__ outh) {
  const int n4 = B_ * H_ * T_ / 4;
  for (int i4 = blockIdx.x * 256 + threadIdx.x; i4 < n4; i4 += gridDim.x * 256) {
    const int idx = i4 << 2;
    const int t = idx & (T_ - 1);
    const int bh = idx >> 12;
    const float carry = cin[((size_t)(bh >> 8) * NCH + (t >> 5)) * H_ + (bh & 255)];
    float4 clv = reinterpret_cast<const float4*>(cl)[i4];
    uint2 pv = reinterpret_cast<const uint2*>(pb)[i4];
    uint2 ov = reinterpret_cast<const uint2*>(ob)[i4];
    const float c0 = clv.x + bf2f((ushort_t)(pv.x & 0xffff)) * carry;
    const float c1 = clv.y + bf2f((ushort_t)(pv.x >> 16)) * carry;
    const float c2 = clv.z + bf2f((ushort_t)(pv.y & 0xffff)) * carry;
    const float c3 = clv.w + bf2f((ushort_t)(pv.y >> 16)) * carry;
    float4 cv = make_float4(c0, c1, c2, c3);
    float4 hv = make_float4(bf2f((ushort_t)(ov.x & 0xffff)) * c0,
                            bf2f((ushort_t)(ov.x >> 16)) * c1,
                            bf2f((ushort_t)(ov.y & 0xffff)) * c2,
                            bf2f((ushort_t)(ov.y >> 16)) * c3);
    reinterpret_cast<float4*>(outc)[i4] = cv;
    reinterpret_cast<float4*>(outh)[i4] = hv;
  }
}

extern "C" void kernel_launch(void* const* d_in, const int* in_sizes, int n_in,
                              void* d_out, int out_size, void* d_ws, size_t ws_size,
                              hipStream_t stream) {
  const float* x  = (const float*)d_in[0];
  const float* Wz = (const float*)d_in[1];
  const float* bz = (const float*)d_in[2];
  const float* Wf = (const float*)d_in[3];
  const float* bfv= (const float*)d_in[4];
  const float* Wo = (const float*)d_in[5];
  const float* bo = (const float*)d_in[6];

  float* outh = (float*)d_out;                        // [B][H][T]
  float* outc = outh + (size_t)B_ * H_ * T_;          // [B][H][T]

  constexpr size_t XQ_OFF  = 0;                       // 33,554,432
  constexpr size_t AQ_OFF  = 33554432;                //    786,432
  constexpr size_t CL_OFF  = 34340864;                // 33,554,432 (c_local fp32)
  constexpr size_t PB_OFF  = 67895296;                // 16,777,216 (cumprod bf16)
  constexpr size_t OB_OFF  = 84672512;                // 16,777,216 (o bf16)
  constexpr size_t AGP_OFF = 101449728;               //  1,048,576
  constexpr size_t AGC_OFF = 102498304;               //  1,048,576
  constexpr size_t CIN_OFF = 103546880;               //  1,048,576
  constexpr size_t WS_NEED = 104595456;
  if (ws_size < WS_NEED) return;

  ushort_t* xq = (ushort_t*)((char*)d_ws + XQ_OFF);
  ushort_t* aq = (ushort_t*)((char*)d_ws + AQ_OFF);
  float* clb   = (float*)((char*)d_ws + CL_OFF);
  ushort_t* pbb= (ushort_t*)((char*)d_ws + PB_OFF);
  ushort_t* ob = (ushort_t*)((char*)d_ws + OB_OFF);
  float* aggP  = (float*)((char*)d_ws + AGP_OFF);
  float* aggC  = (float*)((char*)d_ws + AGC_OFF);
  float* cin   = (float*)((char*)d_ws + CIN_OFF);

  qrnn_pack_x<<<dim3(T_ / 128, C_ / 32, B_), 256, 0, stream>>>(x, xq);
  qrnn_pack_w<<<dim3(192), 256, 0, stream>>>(Wz, Wf, Wo, aq);
  qrnn_g<<<dim3(1024), 512, 0, stream>>>(aq, xq, bz, bfv, bo, clb, pbb, ob, aggP, aggC);
  qrnn_s2<<<dim3(B_), 256, 0, stream>>>(aggP, aggC, cin);
  qrnn_s3<<<dim3(2048), 256, 0, stream>>>(clb, pbb, ob, cin, outc, outh);
}